// Round 1
// 290.184 us; speedup vs baseline: 1.0838x; 1.0838x over previous
//
#include <hip/hip_runtime.h>
#include <hip/hip_bf16.h>

#define NB 32
#define NC 256
#define NH 64
#define NW 64

typedef unsigned short u16;

// ---- intermediates in static device globals (ws_size-independent) ----
__device__ int   g_mode;                    // 1 = bf16 inputs/outputs, 0 = f32
__device__ float g_cmeanp[NB * 16 * 4096];  // per-(b,cg) partial channel-sums (scaled 1/256)
__device__ float g_yp[NB * 16 * 16 * 128];  // per-(b,cg) partial y: [b][cg][m][l]
__device__ float g_pooled[NB * NC];         // channel means
__device__ float g_fch[NB * NC];
__device__ float g_fsa[NB * 4096];
__device__ float g_sh[NB * NC * 64];
__device__ float g_sw[NB * NC * 64];

__device__ __forceinline__ float bf2f(unsigned int u) {
    union { unsigned int i; float f; } v; v.i = u << 16; return v.f;
}
__device__ __forceinline__ u16 f2bf(float f) {
    union { float f; unsigned int i; } v; v.f = f;
    unsigned int i = v.i;
    unsigned int r = (i + 0x7fffu + ((i >> 16) & 1u)) >> 16;   // RNE
    return (u16)r;
}
__device__ __forceinline__ unsigned int pack2(float a, float b) {
    return (unsigned int)f2bf(a) | ((unsigned int)f2bf(b) << 16);
}
__device__ __forceinline__ float sigmoidf_(float x) {
    return 1.f / (1.f + expf(-x));
}

// load 8 consecutive x elements starting at element index i8*8 (mode-opaque)
__device__ __forceinline__ void loadx8(const void* x, size_t i8, int mode, float* v) {
    if (mode) {
        const uint4 u = ((const uint4*)x)[i8];
        v[0] = bf2f(u.x & 0xffffu); v[1] = bf2f(u.x >> 16);
        v[2] = bf2f(u.y & 0xffffu); v[3] = bf2f(u.y >> 16);
        v[4] = bf2f(u.z & 0xffffu); v[5] = bf2f(u.z >> 16);
        v[6] = bf2f(u.w & 0xffffu); v[7] = bf2f(u.w >> 16);
    } else {
        const float4 a = ((const float4*)x)[i8 * 2];
        const float4 b = ((const float4*)x)[i8 * 2 + 1];
        v[0] = a.x; v[1] = a.y; v[2] = a.z; v[3] = a.w;
        v[4] = b.x; v[5] = b.y; v[6] = b.z; v[7] = b.w;
    }
}
__device__ __forceinline__ float loadw(const void* p, int i, int mode) {
    return mode ? bf2f((unsigned int)((const u16*)p)[i]) : ((const float*)p)[i];
}
__device__ __forceinline__ void store8(void* o, size_t i8, int mode, const float* v) {
    if (mode) {
        uint4 u;
        u.x = pack2(v[0], v[1]);
        u.y = pack2(v[2], v[3]);
        u.z = pack2(v[4], v[5]);
        u.w = pack2(v[6], v[7]);
        ((uint4*)o)[i8] = u;
    } else {
        ((float4*)o)[i8 * 2]     = make_float4(v[0], v[1], v[2], v[3]);
        ((float4*)o)[i8 * 2 + 1] = make_float4(v[4], v[5], v[6], v[7]);
    }
}

// ---------------------------------------------------------------------------
// Kernel A: block = (cg, b); 4 waves, each owns 4 channels.
//  - inline dtype sniff (every block classifies the SAME first 2048 even u16s
//    -> deterministic agreement; block (0,0) publishes g_mode for kB/kC)
//  - row/col sums as before
//  - NEW: emits per-cg partial y (w10 slice @ cat_local, cat lives in LDS) and
//    per-channel pooled means; g_catT eliminated.
// ---------------------------------------------------------------------------
__global__ __launch_bounds__(256) void kA(const void* __restrict__ x,
                                          const void* __restrict__ w10) {
    __shared__ unsigned int sliceP[4][2048];   // bf16x2-packed cmean partials (32 KB)
    __shared__ float rowsum[16 * 64];          // 4 KB
    __shared__ float colsum[16 * 64];          // 4 KB
    __shared__ float w10s[256];                // w10[m][cg*16+lc] slice (1 KB)
    __shared__ int scnt;

    const int t  = threadIdx.x;
    const int ln = t & 63, wv = t >> 6;
    const int cg = blockIdx.x;          // 0..15
    const int b  = blockIdx.y;          // 0..31

    // ---- inline sniff: identical classifier to the old kSniff ----
    if (t == 0) scnt = 0;
    __syncthreads();
    {
        const u16* xr = (const u16*)x;
        int local = 0;
#pragma unroll
        for (int i = 0; i < 8; ++i) {
            const u16 w = xr[(t * 8 + i) * 2];   // even u16 indices (first 8 KB)
            const unsigned e = (w >> 7) & 0xffu;
            if (w == 0 || (e >= 0x40u && e <= 0x90u)) ++local;
        }
        atomicAdd(&scnt, local);
    }
    __syncthreads();
    const int mode = (scnt >= 1536) ? 1 : 0;     // >=75% of 2048
    if ((blockIdx.x | blockIdx.y) == 0 && t == 0) g_mode = mode;

    // stage this cg's w10 slice: w10s[m*16+lc] = w10[m][cg*16+lc]
    w10s[t] = loadw(w10, (t >> 4) * NC + cg * 16 + (t & 15), mode);

    float colacc[4][8];
#pragma unroll
    for (int cc = 0; cc < 4; ++cc)
#pragma unroll
        for (int k = 0; k < 8; ++k) colacc[cc][k] = 0.f;

    const int ch0 = cg * 16 + wv * 4;   // this wave's first channel
    const size_t i8base = (((size_t)(b * NC + ch0)) << 9) + ln;   // /8 units

    for (int p = 0; p < 8; ++p) {       // 8 passes of 512 elements (8 rows)
        float cme[8];
#pragma unroll
        for (int k = 0; k < 8; ++k) cme[k] = 0.f;
#pragma unroll
        for (int cc = 0; cc < 4; ++cc) {
            float v[8];
            loadx8(x, i8base + (((size_t)cc) << 9) + p * 64, mode, v);
#pragma unroll
            for (int k = 0; k < 8; ++k) {
                cme[k] += v[k];
                colacc[cc][k] += v[k];
            }
            // row sum: this 8-lane group covers row p*8 + ln/8
            float s = ((v[0] + v[1]) + (v[2] + v[3])) + ((v[4] + v[5]) + (v[6] + v[7]));
            s += __shfl_xor(s, 1);
            s += __shfl_xor(s, 2);
            s += __shfl_xor(s, 4);
            if ((ln & 7) == 0)
                rowsum[(wv * 4 + cc) * 64 + p * 8 + (ln >> 3)] = s;
        }
        // each (wave, position) slot written exactly once -> no init needed
        uint4 pk;
        pk.x = pack2(cme[0], cme[1]);
        pk.y = pack2(cme[2], cme[3]);
        pk.z = pack2(cme[4], cme[5]);
        pk.w = pack2(cme[6], cme[7]);
        *(uint4*)&sliceP[wv][p * 256 + ln * 4] = pk;
    }

    // column totals: sum over lanes differing in bits 3..5 (row-strip index)
#pragma unroll
    for (int cc = 0; cc < 4; ++cc)
#pragma unroll
        for (int k = 0; k < 8; ++k) {
            float v = colacc[cc][k];
            v += __shfl_xor(v, 8);
            v += __shfl_xor(v, 16);
            v += __shfl_xor(v, 32);
            colacc[cc][k] = v;
        }
    if (ln < 8) {                       // lane ln holds cols ln*8 .. ln*8+7
#pragma unroll
        for (int cc = 0; cc < 4; ++cc) {
            *(float4*)&colsum[(wv * 4 + cc) * 64 + ln * 8] =
                make_float4(colacc[cc][0], colacc[cc][1], colacc[cc][2], colacc[cc][3]);
            *(float4*)&colsum[(wv * 4 + cc) * 64 + ln * 8 + 4] =
                make_float4(colacc[cc][4], colacc[cc][5], colacc[cc][6], colacc[cc][7]);
        }
    }
    __syncthreads();

    // (a) cmean partial for this cg: unpack 4 waves' slices, sum, scale 1/256
    {
        const int u0 = t * 8;           // 8 u32 = 16 positions per thread
        float acc[16];
#pragma unroll
        for (int k = 0; k < 16; ++k) acc[k] = 0.f;
#pragma unroll
        for (int w = 0; w < 4; ++w) {
            const uint4 qa = *(const uint4*)&sliceP[w][u0];
            const uint4 qb = *(const uint4*)&sliceP[w][u0 + 4];
            const unsigned int uu[8] = {qa.x, qa.y, qa.z, qa.w, qb.x, qb.y, qb.z, qb.w};
#pragma unroll
            for (int k = 0; k < 8; ++k) {
                acc[2 * k]     += bf2f(uu[k] & 0xffffu);
                acc[2 * k + 1] += bf2f(uu[k] >> 16);
            }
        }
        const float invC = 1.f / 256.f;
        float* dst = g_cmeanp + (((size_t)(b * 16 + cg)) << 12) + t * 16;
#pragma unroll
        for (int k4 = 0; k4 < 4; ++k4)
            *(float4*)(dst + k4 * 4) = make_float4(acc[k4 * 4] * invC,
                                                   acc[k4 * 4 + 1] * invC,
                                                   acc[k4 * 4 + 2] * invC,
                                                   acc[k4 * 4 + 3] * invC);
    }

    // (b) pooled (channel means) = sum_l rowsum[lc][l] / 4096
    {
        const int lc = t >> 4, j = t & 15;
        const float* rs = rowsum + lc * 64 + j * 4;
        float s = (rs[0] + rs[1]) + (rs[2] + rs[3]);
        s += __shfl_xor(s, 1);
        s += __shfl_xor(s, 2);
        s += __shfl_xor(s, 4);
        s += __shfl_xor(s, 8);
        if (j == 0) g_pooled[b * NC + cg * 16 + lc] = s * (1.f / 4096.f);
    }

    // (c) partial y: yp[m][l] = sum_lc w10s[m][lc] * cat_local[lc][l] / 64
    {
        const int m = t >> 4, l0 = (t & 15) * 8;     // 8 consecutive l's
        const float* base = (l0 < 64) ? (rowsum + l0) : (colsum + l0 - 64);
        float acc[8];
#pragma unroll
        for (int k = 0; k < 8; ++k) acc[k] = 0.f;
#pragma unroll
        for (int lc = 0; lc < 16; ++lc) {
            const float wvv = w10s[m * 16 + lc];
            const float4 s0 = *(const float4*)(base + lc * 64);
            const float4 s1 = *(const float4*)(base + lc * 64 + 4);
            acc[0] = fmaf(wvv, s0.x, acc[0]);
            acc[1] = fmaf(wvv, s0.y, acc[1]);
            acc[2] = fmaf(wvv, s0.z, acc[2]);
            acc[3] = fmaf(wvv, s0.w, acc[3]);
            acc[4] = fmaf(wvv, s1.x, acc[4]);
            acc[5] = fmaf(wvv, s1.y, acc[5]);
            acc[6] = fmaf(wvv, s1.z, acc[6]);
            acc[7] = fmaf(wvv, s1.w, acc[7]);
        }
        const float inv64 = 1.f / 64.f;
        float* dst = g_yp + ((((size_t)b * 16 + cg) * 16 + m) << 7) + l0;
        *(float4*)dst =
            make_float4(acc[0] * inv64, acc[1] * inv64, acc[2] * inv64, acc[3] * inv64);
        *(float4*)(dst + 4) =
            make_float4(acc[4] * inv64, acc[5] * inv64, acc[6] * inv64, acc[7] * inv64);
    }
}

// ---------------------------------------------------------------------------
// Kernel B: grid (4, NB). bx = half*2 + csplit.
//   all blocks: y(half) = BN+ReLU(sum_cg yp)  [coalesced 16-way partial sum],
//               s(csplit's 128 ch),
//               f_sa rows bx*16..bx*16+15 (cmean reduce split 4-way w/ halo).
//   bx==0 additionally: f_ch from precomputed pooled (conv1d K=5).
// ---------------------------------------------------------------------------
__global__ __launch_bounds__(256) void kB(
    const void* __restrict__ w11,
    const void* __restrict__ bn_gamma, const void* __restrict__ bn_beta,
    const void* __restrict__ bn_mean, const void* __restrict__ bn_var,
    const void* __restrict__ w20, const void* __restrict__ w21) {

    __shared__ float w11_lds[2048];       // this csplit's 128 rows [c][16] (8 KB)
    __shared__ float y_lds[16 * 65];
    __shared__ float cm[18 * 64];         // this block's cm rows (+halo)
    __shared__ float pooled[260];         // bx==0 only
    __shared__ float bnA[16], bnBv[16];

    const int t  = threadIdx.x;
    const int bx = blockIdx.x;
    const int half = bx >> 1, csplit = bx & 1;
    const int b  = blockIdx.y;
    const int mode = g_mode;

    for (int j = t; j < 2048; j += 256)
        w11_lds[j] = loadw(w11, csplit * 2048 + j, mode);
    if (t < 16) {
        const float inv = rsqrtf(loadw(bn_var, t, mode) + 1e-5f) *
                          loadw(bn_gamma, t, mode);
        bnA[t]  = inv;
        bnBv[t] = loadw(bn_beta, t, mode) - loadw(bn_mean, t, mode) * inv;
    }
    __syncthreads();

    // y[m][l] = BN+ReLU( sum_cg yp[b][cg][m][half*64+l] ) — coalesced
    {
        const int l = t & 63;
        const float* src0 = g_yp + ((size_t)b << 15) + half * 64 + l;
#pragma unroll
        for (int r = 0; r < 4; ++r) {
            const int m = r * 4 + (t >> 6);
            const float* src = src0 + m * 128;
            float s = 0.f;
#pragma unroll
            for (int cgi = 0; cgi < 16; ++cgi)
                s += src[cgi * 2048];
            y_lds[m * 65 + l] = fmaxf(fmaf(s, bnA[m], bnBv[m]), 0.f);  // BN+ReLU
        }
    }
    __syncthreads();

    // s = sigmoid(w11 @ y) for this csplit's 128 channels
    {
        const int h = t & 63, q = t >> 6;
        float yr[16];
#pragma unroll
        for (int mm = 0; mm < 16; ++mm) yr[mm] = y_lds[mm * 65 + h];
        float* sout = half ? g_sw : g_sh;
        const size_t sb = ((size_t)b) * NC * 64;
        for (int ci = 0; ci < 32; ++ci) {
            const int cl = q * 32 + ci;                 // local 0..127
            const float4* wrow = (const float4*)(w11_lds + cl * 16);
            const float4 w0 = wrow[0], w1 = wrow[1], w2 = wrow[2], w3 = wrow[3];
            float acc;
            acc = fmaf(w0.x, yr[0], w0.y * yr[1]);
            acc = fmaf(w0.z, yr[2], acc); acc = fmaf(w0.w, yr[3], acc);
            acc = fmaf(w1.x, yr[4], acc); acc = fmaf(w1.y, yr[5], acc);
            acc = fmaf(w1.z, yr[6], acc); acc = fmaf(w1.w, yr[7], acc);
            acc = fmaf(w2.x, yr[8], acc); acc = fmaf(w2.y, yr[9], acc);
            acc = fmaf(w2.z, yr[10], acc); acc = fmaf(w2.w, yr[11], acc);
            acc = fmaf(w3.x, yr[12], acc); acc = fmaf(w3.y, yr[13], acc);
            acc = fmaf(w3.z, yr[14], acc); acc = fmaf(w3.w, yr[15], acc);
            sout[sb + (size_t)(csplit * 128 + cl) * 64 + h] = sigmoidf_(acc);
        }
    }

    // f_sa rows r0..r0+15: reduce 16 cmean partials (rows + halo), conv3x3+sigmoid
    {
        const int r0 = bx * 16;
        const int c0 = (r0 == 0) ? 0 : (r0 - 1);
        const int c1 = (r0 + 16 > 63) ? 63 : (r0 + 16);
        const int n  = (c1 - c0 + 1) * 64;
        const float* srcb = g_cmeanp + (((size_t)b * 16) << 12) + c0 * 64;
        for (int j = t; j < n; j += 256) {
            float s = 0.f;
#pragma unroll
            for (int gcg = 0; gcg < 16; ++gcg)
                s += srcb[((size_t)gcg << 12) + j];
            cm[j] = s;
        }
        __syncthreads();
        float w21f[9];
#pragma unroll
        for (int k = 0; k < 9; ++k) w21f[k] = loadw(w21, k, mode);
#pragma unroll
        for (int rr = 0; rr < 4; ++rr) {
            const int j  = rr * 256 + t;                // 0..1023
            const int hh = r0 + (j >> 6), ww = j & 63;
            float acc = 0.f;
#pragma unroll
            for (int dy = 0; dy < 3; ++dy) {
                const int hy = hh + dy - 1;
                if (hy < 0 || hy > 63) continue;
#pragma unroll
                for (int dx = 0; dx < 3; ++dx) {
                    const int wx = ww + dx - 1;
                    if (wx < 0 || wx > 63) continue;
                    acc = fmaf(w21f[dy * 3 + dx], cm[(hy - c0) * 64 + wx], acc);
                }
            }
            g_fsa[b * 4096 + hh * 64 + ww] = sigmoidf_(acc);
        }
    }

    // f_ch: conv1d K=5 SAME over channels of precomputed pooled
    if (bx == 0) {
        pooled[2 + t] = g_pooled[b * NC + t];
        if (t < 2) { pooled[t] = 0.f; pooled[258 + t] = 0.f; }
        __syncthreads();
        float w20f[5];
#pragma unroll
        for (int k = 0; k < 5; ++k) w20f[k] = loadw(w20, k, mode);
        float acc = 0.f;
#pragma unroll
        for (int k = 0; k < 5; ++k) acc = fmaf(w20f[k], pooled[t + k], acc);
        g_fch[b * NC + t] = acc;
    }
}

// ---------------------------------------------------------------------------
// Kernel C: out = x * (f_ch + s_h*s_w + f_sa), 8 elements per thread.
// (Unchanged — BW-bound and coalesced.)
// ---------------------------------------------------------------------------
__global__ __launch_bounds__(256) void kC(const void* __restrict__ x,
                                          void* __restrict__ out) {
    const unsigned e = blockIdx.x * 256 + threadIdx.x;   // < 2^22
    const int w0 = (e & 7) << 3;
    const int h  = (e >> 3) & 63;
    const int c  = (e >> 9) & 255;
    const int b  = e >> 17;
    const int mode = g_mode;

    float v[8];
    loadx8(x, e, mode, v);

    const float fc = g_fch[b * NC + c];
    const float sh = g_sh[((size_t)(b * NC + c)) * 64 + h];
    const float* swp = g_sw + ((size_t)(b * NC + c)) * 64 + w0;
    const float* fsp = g_fsa + (size_t)b * 4096 + h * 64 + w0;
    const float4 swa = *(const float4*)(swp);
    const float4 swb = *(const float4*)(swp + 4);
    const float4 fsa = *(const float4*)(fsp);
    const float4 fsb = *(const float4*)(fsp + 4);

    float r[8];
    r[0] = v[0] * (fc + sh * swa.x + fsa.x);
    r[1] = v[1] * (fc + sh * swa.y + fsa.y);
    r[2] = v[2] * (fc + sh * swa.z + fsa.z);
    r[3] = v[3] * (fc + sh * swa.w + fsa.w);
    r[4] = v[4] * (fc + sh * swb.x + fsb.x);
    r[5] = v[5] * (fc + sh * swb.y + fsb.y);
    r[6] = v[6] * (fc + sh * swb.z + fsb.z);
    r[7] = v[7] * (fc + sh * swb.w + fsb.w);

    store8(out, e, mode, r);
}

extern "C" void kernel_launch(void* const* d_in, const int* in_sizes, int n_in,
                              void* d_out, int out_size, void* d_ws, size_t ws_size,
                              hipStream_t stream) {
    const void* x        = d_in[0];
    const void* w10      = d_in[1];
    const void* w11      = d_in[2];
    const void* bn_gamma = d_in[3];
    const void* bn_beta  = d_in[4];
    const void* bn_mean  = d_in[5];
    const void* bn_var   = d_in[6];
    const void* w20      = d_in[7];
    const void* w21      = d_in[8];

    kA<<<dim3(16, NB), 256, 0, stream>>>(x, w10);
    kB<<<dim3(4, NB), 256, 0, stream>>>(w11, bn_gamma, bn_beta,
                                        bn_mean, bn_var, w20, w21);
    kC<<<(NB * NC * NH * NW / 8) / 256, 256, 0, stream>>>(x, d_out);
}

// Round 2
// 289.037 us; speedup vs baseline: 1.0881x; 1.0040x over previous
//
#include <hip/hip_runtime.h>
#include <hip/hip_bf16.h>

#define NB 32
#define NC 256
#define NH 64
#define NW 64

typedef unsigned short u16;

// ---- intermediates in static device globals (ws_size-independent) ----
__device__ int   g_mode;                        // 1 = bf16 inputs/outputs, 0 = f32
__device__ unsigned int g_cmeanpU[NB * 16 * 2048]; // per-(b,cg) partial channel-sums, bf16x2 (scaled 1/256)
__device__ float g_yp[NB * 16 * 16 * 128];      // per-(b,cg) partial y: [b][cg][m][l]
__device__ float g_pooled[NB * NC];             // channel means
__device__ float g_fch[NB * NC];
__device__ float g_fsa[NB * 4096];
__device__ float g_sh[NB * NC * 64];
__device__ float g_sw[NB * NC * 64];

__device__ __forceinline__ float bf2f(unsigned int u) {
    union { unsigned int i; float f; } v; v.i = u << 16; return v.f;
}
__device__ __forceinline__ u16 f2bf(float f) {
    union { float f; unsigned int i; } v; v.f = f;
    unsigned int i = v.i;
    unsigned int r = (i + 0x7fffu + ((i >> 16) & 1u)) >> 16;   // RNE
    return (u16)r;
}
__device__ __forceinline__ unsigned int pack2(float a, float b) {
    return (unsigned int)f2bf(a) | ((unsigned int)f2bf(b) << 16);
}
__device__ __forceinline__ float sigmoidf_(float x) {
    return 1.f / (1.f + expf(-x));
}

// load 8 consecutive x elements starting at element index i8*8 (mode-opaque)
__device__ __forceinline__ void loadx8(const void* x, size_t i8, int mode, float* v) {
    if (mode) {
        const uint4 u = ((const uint4*)x)[i8];
        v[0] = bf2f(u.x & 0xffffu); v[1] = bf2f(u.x >> 16);
        v[2] = bf2f(u.y & 0xffffu); v[3] = bf2f(u.y >> 16);
        v[4] = bf2f(u.z & 0xffffu); v[5] = bf2f(u.z >> 16);
        v[6] = bf2f(u.w & 0xffffu); v[7] = bf2f(u.w >> 16);
    } else {
        const float4 a = ((const float4*)x)[i8 * 2];
        const float4 b = ((const float4*)x)[i8 * 2 + 1];
        v[0] = a.x; v[1] = a.y; v[2] = a.z; v[3] = a.w;
        v[4] = b.x; v[5] = b.y; v[6] = b.z; v[7] = b.w;
    }
}
__device__ __forceinline__ float loadw(const void* p, int i, int mode) {
    return mode ? bf2f((unsigned int)((const u16*)p)[i]) : ((const float*)p)[i];
}
__device__ __forceinline__ void store8(void* o, size_t i8, int mode, const float* v) {
    if (mode) {
        uint4 u;
        u.x = pack2(v[0], v[1]);
        u.y = pack2(v[2], v[3]);
        u.z = pack2(v[4], v[5]);
        u.w = pack2(v[6], v[7]);
        ((uint4*)o)[i8] = u;
    } else {
        ((float4*)o)[i8 * 2]     = make_float4(v[0], v[1], v[2], v[3]);
        ((float4*)o)[i8 * 2 + 1] = make_float4(v[4], v[5], v[6], v[7]);
    }
}

// ---------------------------------------------------------------------------
// Kernel A: block = (cg, b); 4 waves, each owns 4 channels.
//  - inline dtype sniff (every block classifies the SAME first 2048 even u16s
//    -> deterministic agreement; block (0,0) publishes g_mode for kB/kC)
//  - row/col sums; per-cg partial y (w10 slice @ cat_local); pooled means;
//  - cmean partials now written bf16x2-PACKED (halves that stream).
// ---------------------------------------------------------------------------
__global__ __launch_bounds__(256) void kA(const void* __restrict__ x,
                                          const void* __restrict__ w10) {
    __shared__ unsigned int sliceP[4][2048];   // bf16x2-packed cmean partials (32 KB)
    __shared__ float rowsum[16 * 64];          // 4 KB
    __shared__ float colsum[16 * 64];          // 4 KB
    __shared__ float w10s[256];                // w10[m][cg*16+lc] slice (1 KB)
    __shared__ int scnt;

    const int t  = threadIdx.x;
    const int ln = t & 63, wv = t >> 6;
    const int cg = blockIdx.x;          // 0..15
    const int b  = blockIdx.y;          // 0..31

    // ---- inline sniff ----
    if (t == 0) scnt = 0;
    __syncthreads();
    {
        const u16* xr = (const u16*)x;
        int local = 0;
#pragma unroll
        for (int i = 0; i < 8; ++i) {
            const u16 w = xr[(t * 8 + i) * 2];   // even u16 indices (first 8 KB)
            const unsigned e = (w >> 7) & 0xffu;
            if (w == 0 || (e >= 0x40u && e <= 0x90u)) ++local;
        }
        atomicAdd(&scnt, local);
    }
    __syncthreads();
    const int mode = (scnt >= 1536) ? 1 : 0;     // >=75% of 2048
    if ((blockIdx.x | blockIdx.y) == 0 && t == 0) g_mode = mode;

    // stage this cg's w10 slice: w10s[m*16+lc] = w10[m][cg*16+lc]
    w10s[t] = loadw(w10, (t >> 4) * NC + cg * 16 + (t & 15), mode);

    float colacc[4][8];
#pragma unroll
    for (int cc = 0; cc < 4; ++cc)
#pragma unroll
        for (int k = 0; k < 8; ++k) colacc[cc][k] = 0.f;

    const int ch0 = cg * 16 + wv * 4;   // this wave's first channel
    const size_t i8base = (((size_t)(b * NC + ch0)) << 9) + ln;   // /8 units

    for (int p = 0; p < 8; ++p) {       // 8 passes of 512 elements (8 rows)
        float cme[8];
#pragma unroll
        for (int k = 0; k < 8; ++k) cme[k] = 0.f;
#pragma unroll
        for (int cc = 0; cc < 4; ++cc) {
            float v[8];
            loadx8(x, i8base + (((size_t)cc) << 9) + p * 64, mode, v);
#pragma unroll
            for (int k = 0; k < 8; ++k) {
                cme[k] += v[k];
                colacc[cc][k] += v[k];
            }
            // row sum: this 8-lane group covers row p*8 + ln/8
            float s = ((v[0] + v[1]) + (v[2] + v[3])) + ((v[4] + v[5]) + (v[6] + v[7]));
            s += __shfl_xor(s, 1);
            s += __shfl_xor(s, 2);
            s += __shfl_xor(s, 4);
            if ((ln & 7) == 0)
                rowsum[(wv * 4 + cc) * 64 + p * 8 + (ln >> 3)] = s;
        }
        // each (wave, position) slot written exactly once -> no init needed
        uint4 pk;
        pk.x = pack2(cme[0], cme[1]);
        pk.y = pack2(cme[2], cme[3]);
        pk.z = pack2(cme[4], cme[5]);
        pk.w = pack2(cme[6], cme[7]);
        *(uint4*)&sliceP[wv][p * 256 + ln * 4] = pk;
    }

    // column totals: sum over lanes differing in bits 3..5 (row-strip index)
#pragma unroll
    for (int cc = 0; cc < 4; ++cc)
#pragma unroll
        for (int k = 0; k < 8; ++k) {
            float v = colacc[cc][k];
            v += __shfl_xor(v, 8);
            v += __shfl_xor(v, 16);
            v += __shfl_xor(v, 32);
            colacc[cc][k] = v;
        }
    if (ln < 8) {                       // lane ln holds cols ln*8 .. ln*8+7
#pragma unroll
        for (int cc = 0; cc < 4; ++cc) {
            *(float4*)&colsum[(wv * 4 + cc) * 64 + ln * 8] =
                make_float4(colacc[cc][0], colacc[cc][1], colacc[cc][2], colacc[cc][3]);
            *(float4*)&colsum[(wv * 4 + cc) * 64 + ln * 8 + 4] =
                make_float4(colacc[cc][4], colacc[cc][5], colacc[cc][6], colacc[cc][7]);
        }
    }
    __syncthreads();

    // (a) cmean partial for this cg: unpack 4 waves' slices, sum, scale 1/256,
    //     re-pack bf16x2, store 8 uints (16 positions) per thread.
    {
        const int u0 = t * 8;           // 8 u32 = 16 positions per thread
        float acc[16];
#pragma unroll
        for (int k = 0; k < 16; ++k) acc[k] = 0.f;
#pragma unroll
        for (int w = 0; w < 4; ++w) {
            const uint4 qa = *(const uint4*)&sliceP[w][u0];
            const uint4 qb = *(const uint4*)&sliceP[w][u0 + 4];
            const unsigned int uu[8] = {qa.x, qa.y, qa.z, qa.w, qb.x, qb.y, qb.z, qb.w};
#pragma unroll
            for (int k = 0; k < 8; ++k) {
                acc[2 * k]     += bf2f(uu[k] & 0xffffu);
                acc[2 * k + 1] += bf2f(uu[k] >> 16);
            }
        }
        const float invC = 1.f / 256.f;
        unsigned int pk[8];
#pragma unroll
        for (int k = 0; k < 8; ++k)
            pk[k] = pack2(acc[2 * k] * invC, acc[2 * k + 1] * invC);
        unsigned int* dst = g_cmeanpU + (((size_t)(b * 16 + cg)) << 11) + t * 8;
        *(uint4*)dst       = make_uint4(pk[0], pk[1], pk[2], pk[3]);
        *(uint4*)(dst + 4) = make_uint4(pk[4], pk[5], pk[6], pk[7]);
    }

    // (b) pooled (channel means) = sum_l rowsum[lc][l] / 4096
    {
        const int lc = t >> 4, j = t & 15;
        const float* rs = rowsum + lc * 64 + j * 4;
        float s = (rs[0] + rs[1]) + (rs[2] + rs[3]);
        s += __shfl_xor(s, 1);
        s += __shfl_xor(s, 2);
        s += __shfl_xor(s, 4);
        s += __shfl_xor(s, 8);
        if (j == 0) g_pooled[b * NC + cg * 16 + lc] = s * (1.f / 4096.f);
    }

    // (c) partial y: yp[m][l] = sum_lc w10s[m][lc] * cat_local[lc][l] / 64
    {
        const int m = t >> 4, l0 = (t & 15) * 8;     // 8 consecutive l's
        const float* base = (l0 < 64) ? (rowsum + l0) : (colsum + l0 - 64);
        float acc[8];
#pragma unroll
        for (int k = 0; k < 8; ++k) acc[k] = 0.f;
#pragma unroll
        for (int lc = 0; lc < 16; ++lc) {
            const float wvv = w10s[m * 16 + lc];
            const float4 s0 = *(const float4*)(base + lc * 64);
            const float4 s1 = *(const float4*)(base + lc * 64 + 4);
            acc[0] = fmaf(wvv, s0.x, acc[0]);
            acc[1] = fmaf(wvv, s0.y, acc[1]);
            acc[2] = fmaf(wvv, s0.z, acc[2]);
            acc[3] = fmaf(wvv, s0.w, acc[3]);
            acc[4] = fmaf(wvv, s1.x, acc[4]);
            acc[5] = fmaf(wvv, s1.y, acc[5]);
            acc[6] = fmaf(wvv, s1.z, acc[6]);
            acc[7] = fmaf(wvv, s1.w, acc[7]);
        }
        const float inv64 = 1.f / 64.f;
        float* dst = g_yp + ((((size_t)b * 16 + cg) * 16 + m) << 7) + l0;
        *(float4*)dst =
            make_float4(acc[0] * inv64, acc[1] * inv64, acc[2] * inv64, acc[3] * inv64);
        *(float4*)(dst + 4) =
            make_float4(acc[4] * inv64, acc[5] * inv64, acc[6] * inv64, acc[7] * inv64);
    }
}

// ---------------------------------------------------------------------------
// Kernel B: grid (8, NB). half = bx>>2 (s_h vs s_w), quarter = bx&3 (64 ch).
//   all blocks: y(half) = BN+ReLU(sum_cg yp) [coalesced], s for 64 channels,
//               f_sa rows bx*8..bx*8+7 (packed cmean reduce w/ halo).
//   bx==0 additionally: f_ch from precomputed pooled (conv1d K=5).
// 256 blocks -> 1 block/CU (was 128): latency-bound stage gets 2x parallelism
// with half the per-block work.
// ---------------------------------------------------------------------------
__global__ __launch_bounds__(256) void kB(
    const void* __restrict__ w11,
    const void* __restrict__ bn_gamma, const void* __restrict__ bn_beta,
    const void* __restrict__ bn_mean, const void* __restrict__ bn_var,
    const void* __restrict__ w20, const void* __restrict__ w21) {

    __shared__ float w11_lds[1024];       // this quarter's 64 rows [c][16] (4 KB)
    __shared__ float y_lds[16 * 65];
    __shared__ float cm[10 * 64];         // this block's cm rows (+halo)
    __shared__ float pooled[260];         // bx==0 only
    __shared__ float bnA[16], bnBv[16];

    const int t  = threadIdx.x;
    const int bx = blockIdx.x;
    const int half = bx >> 2, quarter = bx & 3;
    const int b  = blockIdx.y;
    const int mode = g_mode;

    for (int j = t; j < 1024; j += 256)
        w11_lds[j] = loadw(w11, quarter * 1024 + j, mode);
    if (t < 16) {
        const float inv = rsqrtf(loadw(bn_var, t, mode) + 1e-5f) *
                          loadw(bn_gamma, t, mode);
        bnA[t]  = inv;
        bnBv[t] = loadw(bn_beta, t, mode) - loadw(bn_mean, t, mode) * inv;
    }
    __syncthreads();

    // y[m][l] = BN+ReLU( sum_cg yp[b][cg][m][half*64+l] ) — coalesced
    {
        const int l = t & 63;
        const float* src0 = g_yp + ((size_t)b << 15) + half * 64 + l;
#pragma unroll
        for (int r = 0; r < 4; ++r) {
            const int m = r * 4 + (t >> 6);
            const float* src = src0 + m * 128;
            float s = 0.f;
#pragma unroll
            for (int cgi = 0; cgi < 16; ++cgi)
                s += src[cgi * 2048];
            y_lds[m * 65 + l] = fmaxf(fmaf(s, bnA[m], bnBv[m]), 0.f);  // BN+ReLU
        }
    }
    __syncthreads();

    // s = sigmoid(w11 @ y) for this quarter's 64 channels
    {
        const int h = t & 63, q = t >> 6;
        float yr[16];
#pragma unroll
        for (int mm = 0; mm < 16; ++mm) yr[mm] = y_lds[mm * 65 + h];
        float* sout = half ? g_sw : g_sh;
        const size_t sb = ((size_t)b) * NC * 64;
        for (int ci = 0; ci < 16; ++ci) {
            const int cl = q * 16 + ci;                 // local 0..63
            const float4* wrow = (const float4*)(w11_lds + cl * 16);
            const float4 w0 = wrow[0], w1 = wrow[1], w2 = wrow[2], w3 = wrow[3];
            float acc;
            acc = fmaf(w0.x, yr[0], w0.y * yr[1]);
            acc = fmaf(w0.z, yr[2], acc); acc = fmaf(w0.w, yr[3], acc);
            acc = fmaf(w1.x, yr[4], acc); acc = fmaf(w1.y, yr[5], acc);
            acc = fmaf(w1.z, yr[6], acc); acc = fmaf(w1.w, yr[7], acc);
            acc = fmaf(w2.x, yr[8], acc); acc = fmaf(w2.y, yr[9], acc);
            acc = fmaf(w2.z, yr[10], acc); acc = fmaf(w2.w, yr[11], acc);
            acc = fmaf(w3.x, yr[12], acc); acc = fmaf(w3.y, yr[13], acc);
            acc = fmaf(w3.z, yr[14], acc); acc = fmaf(w3.w, yr[15], acc);
            sout[sb + (size_t)(quarter * 64 + cl) * 64 + h] = sigmoidf_(acc);
        }
    }

    // f_sa rows r0..r0+7: reduce 16 PACKED cmean partials (rows + halo),
    // conv3x3 SAME + sigmoid
    {
        const int r0 = bx * 8;
        const int c0 = (r0 == 0) ? 0 : (r0 - 1);
        const int c1 = (r0 + 8 > 63) ? 63 : (r0 + 8);
        const int nu = (c1 - c0 + 1) * 32;            // uints (2 positions each)
        const unsigned int* srcb =
            g_cmeanpU + (((size_t)b * 16) << 11) + c0 * 32;
        for (int j = t; j < nu; j += 256) {
            float s0 = 0.f, s1 = 0.f;
#pragma unroll
            for (int gcg = 0; gcg < 16; ++gcg) {
                const unsigned int u = srcb[((size_t)gcg << 11) + j];
                s0 += bf2f(u & 0xffffu);
                s1 += bf2f(u >> 16);
            }
            cm[2 * j]     = s0;
            cm[2 * j + 1] = s1;
        }
        __syncthreads();
        float w21f[9];
#pragma unroll
        for (int k = 0; k < 9; ++k) w21f[k] = loadw(w21, k, mode);
#pragma unroll
        for (int rr = 0; rr < 2; ++rr) {
            const int j  = rr * 256 + t;                // 0..511
            const int hh = r0 + (j >> 6), ww = j & 63;
            float acc = 0.f;
#pragma unroll
            for (int dy = 0; dy < 3; ++dy) {
                const int hy = hh + dy - 1;
                if (hy < 0 || hy > 63) continue;
#pragma unroll
                for (int dx = 0; dx < 3; ++dx) {
                    const int wx = ww + dx - 1;
                    if (wx < 0 || wx > 63) continue;
                    acc = fmaf(w21f[dy * 3 + dx], cm[(hy - c0) * 64 + wx], acc);
                }
            }
            g_fsa[b * 4096 + hh * 64 + ww] = sigmoidf_(acc);
        }
    }

    // f_ch: conv1d K=5 SAME over channels of precomputed pooled
    if (bx == 0) {
        pooled[2 + t] = g_pooled[b * NC + t];
        if (t < 2) { pooled[t] = 0.f; pooled[258 + t] = 0.f; }
        __syncthreads();
        float w20f[5];
#pragma unroll
        for (int k = 0; k < 5; ++k) w20f[k] = loadw(w20, k, mode);
        float acc = 0.f;
#pragma unroll
        for (int k = 0; k < 5; ++k) acc = fmaf(w20f[k], pooled[t + k], acc);
        g_fch[b * NC + t] = acc;
    }
}

// ---------------------------------------------------------------------------
// Kernel C: out = x * (f_ch + s_h*s_w + f_sa), 8 elements per thread.
// (Unchanged — BW-bound and coalesced.)
// ---------------------------------------------------------------------------
__global__ __launch_bounds__(256) void kC(const void* __restrict__ x,
                                          void* __restrict__ out) {
    const unsigned e = blockIdx.x * 256 + threadIdx.x;   // < 2^22
    const int w0 = (e & 7) << 3;
    const int h  = (e >> 3) & 63;
    const int c  = (e >> 9) & 255;
    const int b  = e >> 17;
    const int mode = g_mode;

    float v[8];
    loadx8(x, e, mode, v);

    const float fc = g_fch[b * NC + c];
    const float sh = g_sh[((size_t)(b * NC + c)) * 64 + h];
    const float* swp = g_sw + ((size_t)(b * NC + c)) * 64 + w0;
    const float* fsp = g_fsa + (size_t)b * 4096 + h * 64 + w0;
    const float4 swa = *(const float4*)(swp);
    const float4 swb = *(const float4*)(swp + 4);
    const float4 fsa = *(const float4*)(fsp);
    const float4 fsb = *(const float4*)(fsp + 4);

    float r[8];
    r[0] = v[0] * (fc + sh * swa.x + fsa.x);
    r[1] = v[1] * (fc + sh * swa.y + fsa.y);
    r[2] = v[2] * (fc + sh * swa.z + fsa.z);
    r[3] = v[3] * (fc + sh * swa.w + fsa.w);
    r[4] = v[4] * (fc + sh * swb.x + fsb.x);
    r[5] = v[5] * (fc + sh * swb.y + fsb.y);
    r[6] = v[6] * (fc + sh * swb.z + fsb.z);
    r[7] = v[7] * (fc + sh * swb.w + fsb.w);

    store8(out, e, mode, r);
}

extern "C" void kernel_launch(void* const* d_in, const int* in_sizes, int n_in,
                              void* d_out, int out_size, void* d_ws, size_t ws_size,
                              hipStream_t stream) {
    const void* x        = d_in[0];
    const void* w10      = d_in[1];
    const void* w11      = d_in[2];
    const void* bn_gamma = d_in[3];
    const void* bn_beta  = d_in[4];
    const void* bn_mean  = d_in[5];
    const void* bn_var   = d_in[6];
    const void* w20      = d_in[7];
    const void* w21      = d_in[8];

    kA<<<dim3(16, NB), 256, 0, stream>>>(x, w10);
    kB<<<dim3(8, NB), 256, 0, stream>>>(w11, bn_gamma, bn_beta,
                                        bn_mean, bn_var, w20, w21);
    kC<<<(NB * NC * NH * NW / 8) / 256, 256, 0, stream>>>(x, d_out);
}